// Round 8
// baseline (501.966 us; speedup 1.0000x reference)
//
#include <hip/hip_runtime.h>

#define NT 512   // T
#define NB 128   // B
#define ND 256   // D
#define NH 256   // H

typedef _Float16 h2 __attribute__((ext_vector_type(2)));
typedef unsigned int u4 __attribute__((ext_vector_type(4)));
typedef float f4 __attribute__((ext_vector_type(4)));

#if __has_builtin(__builtin_amdgcn_fdot2)
#define DOT2(a, b, c) __builtin_amdgcn_fdot2((a), (b), (c), false)
#else
#define DOT2(a, b, c) (fmaf((float)(a)[0], (float)(b)[0], \
                        fmaf((float)(a)[1], (float)(b)[1], (c))))
#endif

// value-level keep-alive (R4 pattern, correctness-proven): no address taken
#define PIN32(x) do {                               \
    float _f = __builtin_bit_cast(float, (x));      \
    asm volatile("" : "+v"(_f));                    \
    (x) = __builtin_bit_cast(h2, _f);               \
} while (0)

// Unsinkable weight load: volatile asm global_load_dwordx4 with in-asm
// waitcnt. The compiler cannot rematerialize/sink an asm volatile, so the
// result MUST stay register-resident across the 512-step loop (scratch
// spill would be the only alternative, and there is no register pressure).
#define LDW(dst, base, off) \
    asm volatile("global_load_dwordx4 %0, %1, off offset:" #off \
                 "\n\ts_waitcnt vmcnt(0)" \
                 : "=v"(dst) : "v"(base))

// fp32x4 -> two packed half2
#define CVT2(dsta, dstb, src) do {                      \
    const f4 _f = __builtin_bit_cast(f4, (src));        \
    (dsta) = h2{(_Float16)_f[0], (_Float16)_f[1]};      \
    (dstb) = h2{(_Float16)_f[2], (_Float16)_f[3]};      \
} while (0)

// ---------------------------------------------------------------------------
// Phase 1: Z = X @ Wi^T + bh.  Register-tiled fp32 GEMM (unchanged, proven).
// ---------------------------------------------------------------------------
__global__ __launch_bounds__(256) void zprep_kernel(
    const float* __restrict__ X, const float* __restrict__ Wi,
    const float* __restrict__ bh, float* __restrict__ Z)
{
    __shared__ float xsT[64][68];   // [k][m]
    __shared__ float wsT[64][68];   // [k][j]
    const int tid = threadIdx.x;
    const int tm  = tid & 15, tj = tid >> 4;
    const int m0  = blockIdx.x * 64;
    const int j0  = blockIdx.y * 64;
    const int sm  = tid >> 2, kq = tid & 3;

    float acc[4][4] = {};

    for (int c = 0; c < 4; ++c) {
        const int k0 = c * 64;
        const float* xr = X  + (size_t)(m0 + sm) * ND + k0 + kq * 16;
        const float* wr = Wi + (size_t)(j0 + sm) * ND + k0 + kq * 16;
        #pragma unroll
        for (int i = 0; i < 4; ++i) {
            const float4 xv = *(const float4*)(xr + i * 4);
            const float4 wv = *(const float4*)(wr + i * 4);
            const int kk = kq * 16 + i * 4;
            xsT[kk + 0][sm] = xv.x; xsT[kk + 1][sm] = xv.y;
            xsT[kk + 2][sm] = xv.z; xsT[kk + 3][sm] = xv.w;
            wsT[kk + 0][sm] = wv.x; wsT[kk + 1][sm] = wv.y;
            wsT[kk + 2][sm] = wv.z; wsT[kk + 3][sm] = wv.w;
        }
        __syncthreads();

        #pragma unroll 8
        for (int k = 0; k < 64; ++k) {
            const float4 x4 = *(const float4*)&xsT[k][tm * 4];
            const float4 w4 = *(const float4*)&wsT[k][tj * 4];
            acc[0][0] = fmaf(x4.x, w4.x, acc[0][0]);
            acc[0][1] = fmaf(x4.x, w4.y, acc[0][1]);
            acc[0][2] = fmaf(x4.x, w4.z, acc[0][2]);
            acc[0][3] = fmaf(x4.x, w4.w, acc[0][3]);
            acc[1][0] = fmaf(x4.y, w4.x, acc[1][0]);
            acc[1][1] = fmaf(x4.y, w4.y, acc[1][1]);
            acc[1][2] = fmaf(x4.y, w4.z, acc[1][2]);
            acc[1][3] = fmaf(x4.y, w4.w, acc[1][3]);
            acc[2][0] = fmaf(x4.z, w4.x, acc[2][0]);
            acc[2][1] = fmaf(x4.z, w4.y, acc[2][1]);
            acc[2][2] = fmaf(x4.z, w4.z, acc[2][2]);
            acc[2][3] = fmaf(x4.z, w4.w, acc[2][3]);
            acc[3][0] = fmaf(x4.w, w4.x, acc[3][0]);
            acc[3][1] = fmaf(x4.w, w4.y, acc[3][1]);
            acc[3][2] = fmaf(x4.w, w4.z, acc[3][2]);
            acc[3][3] = fmaf(x4.w, w4.w, acc[3][3]);
        }
        __syncthreads();
    }

    const float4 b4 = *(const float4*)&bh[j0 + tj * 4];
    #pragma unroll
    for (int r = 0; r < 4; ++r) {
        float4 o;
        o.x = acc[r][0] + b4.x; o.y = acc[r][1] + b4.y;
        o.z = acc[r][2] + b4.z; o.w = acc[r][3] + b4.w;
        *(float4*)&Z[(size_t)(m0 + tm * 4 + r) * NH + j0 + tj * 4] = o;
    }
}

// ---------------------------------------------------------------------------
// Phase 2: recurrence, fp16 dot2 / fp32 accumulate. One WG / batch row,
// 1024 threads. ks=tid&7 owns a 32-wide k-slice of outputs j0=2jb, 2jb+1.
// Weights loaded via UNSINKABLE asm-volatile global_load_dwordx4 (the
// compiler sank every source-level weight load into the t-loop across R1-R7,
// VGPR_Count 40-88 proving re-fetch). Loads interleaved with fp32->half2
// conversion to cap peak pressure ~90 regs < 128 cap (launch_bounds 1024,4).
// h double-buffered in LDS at slice stride 24 h2 (aligned b128, 8-lane
// broadcast). shfl_xor(1,2,4) reduce, one barrier/step, unconditional z
// prefetch, immediate store -- the R7 structure, which passed.
// ---------------------------------------------------------------------------
__global__ __launch_bounds__(1024, 4) void rnn_step_kernel(
    float* __restrict__ ZO,
    const float* __restrict__ h0,
    const float* __restrict__ Wh)
{
    __shared__ __align__(16) h2 hb[2][8 * 24];   // 8 slices x 16 h2, pad to 24
    const int b   = blockIdx.x;
    const int tid = threadIdx.x;
    const int ks  = tid & 7;
    const int jb  = tid >> 3;
    const int j0  = jb * 2;

    // Wh rows j0 (offsets 0..112) and j0+1 (offsets 1024..1136) from one base
    h2 w0p[16], w1p[16];
    {
        const unsigned long long base =
            (unsigned long long)(Wh + (size_t)j0 * NH + ks * 32);
        u4 q;
        LDW(q, base, 0);    CVT2(w0p[0],  w0p[1],  q);
        LDW(q, base, 16);   CVT2(w0p[2],  w0p[3],  q);
        LDW(q, base, 32);   CVT2(w0p[4],  w0p[5],  q);
        LDW(q, base, 48);   CVT2(w0p[6],  w0p[7],  q);
        LDW(q, base, 64);   CVT2(w0p[8],  w0p[9],  q);
        LDW(q, base, 80);   CVT2(w0p[10], w0p[11], q);
        LDW(q, base, 96);   CVT2(w0p[12], w0p[13], q);
        LDW(q, base, 112);  CVT2(w0p[14], w0p[15], q);
        LDW(q, base, 1024); CVT2(w1p[0],  w1p[1],  q);
        LDW(q, base, 1040); CVT2(w1p[2],  w1p[3],  q);
        LDW(q, base, 1056); CVT2(w1p[4],  w1p[5],  q);
        LDW(q, base, 1072); CVT2(w1p[6],  w1p[7],  q);
        LDW(q, base, 1088); CVT2(w1p[8],  w1p[9],  q);
        LDW(q, base, 1104); CVT2(w1p[10], w1p[11], q);
        LDW(q, base, 1120); CVT2(w1p[12], w1p[13], q);
        LDW(q, base, 1136); CVT2(w1p[14], w1p[15], q);
    }
    #pragma unroll
    for (int i = 0; i < 16; ++i) { PIN32(w0p[i]); PIN32(w1p[i]); }

    if (tid < 128) {
        const float2 hp = *(const float2*)(h0 + (size_t)b * NH + tid * 2);
        hb[0][(tid >> 4) * 24 + (tid & 15)] =
            h2{(_Float16)hp.x, (_Float16)hp.y};
    }

    float2 z2 = *(const float2*)(ZO + (size_t)b * NH + j0);   // t = 0
    __syncthreads();

    int cur = 0;
    for (int t = 0; t < NT; ++t) {
        // this thread's 16 h2 of h (4 x ds_read_b128, aligned, broadcast)
        h2 hh[16];
        const h2* hv = &hb[cur][ks * 24];
        #pragma unroll
        for (int i = 0; i < 4; ++i)
            *(u4*)&hh[4 * i] = *(const u4*)&hv[4 * i];

        // prefetch z for t+1 (hides under the dot)
        float2 z2n = z2;
        if (t + 1 < NT)
            z2n = *(const float2*)(ZO + ((size_t)(t + 1) * NB + b) * NH + j0);

        // dot over this thread's 32-k slice; 4 chains
        float a0 = 0.f, a1 = 0.f, c0 = 0.f, c1 = 0.f;
        #pragma unroll
        for (int i = 0; i < 8; ++i) {
            a0 = DOT2(w0p[i],     hh[i],     a0);
            a1 = DOT2(w1p[i],     hh[i],     a1);
            c0 = DOT2(w0p[i + 8], hh[i + 8], c0);
            c1 = DOT2(w1p[i + 8], hh[i + 8], c1);
        }
        float s0 = a0 + c0;
        float s1 = a1 + c1;

        // reduce the 8 k-slice partials (lanes differing in bits 0..2)
        s0 += __shfl_xor(s0, 1); s1 += __shfl_xor(s1, 1);
        s0 += __shfl_xor(s0, 2); s1 += __shfl_xor(s1, 2);
        s0 += __shfl_xor(s0, 4); s1 += __shfl_xor(s1, 4);

        if (ks == 0) {
            const float p0 = z2.x + s0;
            const float p1 = z2.y + s1;
            const float hn0 = 1.0f / (1.0f + __expf(-p0));
            const float hn1 = 1.0f / (1.0f + __expf(-p1));
            hb[cur ^ 1][(jb >> 4) * 24 + (jb & 15)] =
                h2{(_Float16)hn0, (_Float16)hn1};
            *(float2*)(ZO + ((size_t)t * NB + b) * NH + j0) =
                make_float2(hn0, hn1);
        }
        z2 = z2n;
        __syncthreads();
        cur ^= 1;
    }
}

extern "C" void kernel_launch(void* const* d_in, const int* in_sizes, int n_in,
                              void* d_out, int out_size, void* d_ws, size_t ws_size,
                              hipStream_t stream) {
    const float* X  = (const float*)d_in[0];
    const float* h0 = (const float*)d_in[1];
    const float* Wi = (const float*)d_in[2];
    const float* Wh = (const float*)d_in[3];
    const float* bh = (const float*)d_in[4];
    float* out = (float*)d_out;

    dim3 zgrid((NT * NB) / 64, NH / 64);
    zprep_kernel<<<zgrid, 256, 0, stream>>>(X, Wi, bh, out);
    rnn_step_kernel<<<NB, 1024, 0, stream>>>(out, h0, Wh);
}